// Round 7
// baseline (233.695 us; speedup 1.0000x reference)
//
#include <hip/hip_runtime.h>
#include <math.h>

#define Bn   4
#define CINc 64
#define Hh   160
#define Ww   160
#define Gg   8
#define HW   (Hh * 160)     // 25600
#define COFF 216

// ---- DCN window split: 6 windows x 12 (g,k)-units (3 k-steps of 32) --------
#define NWIN 6
#define WU   12
#define VROW 100            // vbuf row stride u16 (200B rows: lane*50%32 -> 2-way)

// ---- single-union LDS region (disjoint lifetimes alias) --------------------
// halo   : 100*72 u16 = 14400 B   [stage .. conv MFMA end]   (aliases offsYX)
// offsYX : u32 [64][73] = 18688 B [conv epilogue .. last window issue]
// maskL  : u16 [64][74] =  9472 B [conv epilogue .. last window issue]
// vbuf   : u16 [64][VROW]=12800 B [window issue .. gemm]
// total = 40960 B exactly -> 4 blocks/CU (was 53760 B / 3 blocks)
#define SMEM_U32 10240           // 40960 B
#define MASKL_OFF_U16 9344       // 18688 B / 2
#define VBUF_OFF_U16  14080      // (18688+9472) / 2

typedef short bf16x8 __attribute__((ext_vector_type(8)));
typedef float f32x4  __attribute__((ext_vector_type(4)));

static __device__ __forceinline__ unsigned short f2bf(float f) {
    unsigned int u = __float_as_uint(f);
    u = (u + 0x7fffu + ((u >> 16) & 1u)) >> 16;
    return (unsigned short)u;
}
static __device__ __forceinline__ float bf2f(unsigned short s) {
    return __uint_as_float(((unsigned int)s) << 16);
}
static __device__ __forceinline__ float blo(unsigned int u) {
    return __uint_as_float(u << 16);
}
static __device__ __forceinline__ float bhi(unsigned int u) {
    return __uint_as_float(u & 0xffff0000u);
}

// ---------- Prep v4: LDS-free streaming transpose + weight repacks ----------
// (R5 post-mortem: bench residual is harness-dominated; prep is near enough
//  to its traffic roofline. Unchanged.)
__global__ __launch_bounds__(256)
void prep_kernel(const float* __restrict__ feat, const float* __restrict__ x,
                 const float* __restrict__ w_off, const float* __restrict__ w_dcn,
                 unsigned short* __restrict__ featT, unsigned short* __restrict__ xG,
                 unsigned short* __restrict__ wofrag, unsigned short* __restrict__ wfrag) {
    const int blk = blockIdx.x;
    const int t = threadIdx.x;
    if (blk < 800) {
        const int b  = blk / 200;
        const int q  = (blk % 200) * 32 + (t >> 3);
        const int cj = t & 7;
        const float* fb = feat + (size_t)b * CINc * HW;
        float4 v[8];
        #pragma unroll
        for (int m = 0; m < 8; ++m)
            v[m] = *(const float4*)(fb + (size_t)(cj * 8 + m) * HW + q * 4);
        uint4* dst = (uint4*)featT + ((size_t)b * HW + q * 4) * 8 + cj;
        #pragma unroll
        for (int k = 0; k < 4; ++k) {
            float e[8];
            #pragma unroll
            for (int m = 0; m < 8; ++m) {
                const float4 vv = v[m];
                e[m] = (k == 0) ? vv.x : (k == 1) ? vv.y : (k == 2) ? vv.z : vv.w;
            }
            unsigned int d0, d1, d2, d3;
            asm("v_cvt_pk_bf16_f32 %0, %1, %2" : "=v"(d0) : "v"(e[0]), "v"(e[1]));
            asm("v_cvt_pk_bf16_f32 %0, %1, %2" : "=v"(d1) : "v"(e[2]), "v"(e[3]));
            asm("v_cvt_pk_bf16_f32 %0, %1, %2" : "=v"(d2) : "v"(e[4]), "v"(e[5]));
            asm("v_cvt_pk_bf16_f32 %0, %1, %2" : "=v"(d3) : "v"(e[6]), "v"(e[7]));
            uint4 r4; r4.x = d0; r4.y = d1; r4.z = d2; r4.w = d3;
            dst[(size_t)k * 8] = r4;
        }
    } else if (blk < 1600) {
        const int r  = blk - 800;
        const int bg = r / 25;
        const int q  = (r % 25) * 256 + t;
        const float* xb = x + ((size_t)(bg >> 3) * CINc + (size_t)(bg & 7) * 8) * HW;
        float4 v[8];
        #pragma unroll
        for (int cg = 0; cg < 8; ++cg)
            v[cg] = *(const float4*)(xb + (size_t)cg * HW + q * 4);
        uint4* dst = (uint4*)xG + (size_t)bg * HW + q * 4;
        #pragma unroll
        for (int k = 0; k < 4; ++k) {
            float e[8];
            #pragma unroll
            for (int cg = 0; cg < 8; ++cg) {
                const float4 vv = v[cg];
                e[cg] = (k == 0) ? vv.x : (k == 1) ? vv.y : (k == 2) ? vv.z : vv.w;
            }
            unsigned int d0, d1, d2, d3;
            asm("v_cvt_pk_bf16_f32 %0, %1, %2" : "=v"(d0) : "v"(e[0]), "v"(e[1]));
            asm("v_cvt_pk_bf16_f32 %0, %1, %2" : "=v"(d1) : "v"(e[2]), "v"(e[3]));
            asm("v_cvt_pk_bf16_f32 %0, %1, %2" : "=v"(d2) : "v"(e[4]), "v"(e[5]));
            asm("v_cvt_pk_bf16_f32 %0, %1, %2" : "=v"(d3) : "v"(e[6]), "v"(e[7]));
            uint4 r4; r4.x = d0; r4.y = d1; r4.z = d2; r4.w = d3;
            dst[k] = r4;
        }
    } else {
        for (int e = (blk - 1600) * 256 + t; e < 147456 + 36864; e += 180 * 256) {
            if (e < 147456) {
                const int j    = e & 7;
                const int lane = (e >> 3) & 63;
                const int rest = e >> 9;
                const int mt = rest & 15;
                const int q  = rest >> 4;
                const int ks = q & 1;
                const int kp = q >> 1;
                const int co = mt * 16 + (lane & 15);
                const int ci = ks * 32 + (lane >> 4) * 8 + j;
                float v = (co < COFF) ? w_off[(size_t)co * 576 + ci * 9 + kp] : 0.f;
                wofrag[e] = f2bf(v);
            } else {
                const int e2   = e - 147456;
                const int j    = e2 & 7;
                const int lane = (e2 >> 3) & 63;
                const int mt   = (e2 >> 9) & 3;
                const int ks   = e2 >> 11;
                const int m = mt * 16 + (lane & 15);
                const int k = ks * 32 + (lane >> 4) * 8 + j;
                const int g = k / 72, r = k % 72;
                const int kk = r >> 3, cg = r & 7;
                const int ci = g * 8 + cg;
                wfrag[e2] = f2bf(w_dcn[((size_t)m * CINc + ci) * 9 + kk]);
            }
        }
    }
}

#define BLEND_J(out_, w00, w01, w10, w11, c00, c01, c10, c11) {            \
    float vl_ = (c00) * blo(w00) + (c01) * blo(w01)                        \
              + (c10) * blo(w10) + (c11) * blo(w11);                       \
    float vh_ = (c00) * bhi(w00) + (c01) * bhi(w01)                        \
              + (c10) * bhi(w10) + (c11) * bhi(w11);                       \
    asm("v_cvt_pk_bf16_f32 %0, %1, %2" : "=v"(out_) : "v"(vl_), "v"(vh_)); \
}

// ---------- Fused kernel: 6x12-unit windows, 40960B LDS, 4 blocks/CU --------
// REGISTER DISCIPLINE (R3/R6 lessons): NO s_setprio, NO offset preload
// arrays. Peak live state = proven R1 shape minus half the gather batch.
// Spill tripwire: WRITE_SIZE must stay 25.6 MB.
__global__ __launch_bounds__(256, 4)
void dcnpack_fused(const unsigned short* __restrict__ featT,
                   const unsigned short* __restrict__ xG,
                   const unsigned short* __restrict__ wofrag,
                   const unsigned short* __restrict__ wfrag,
                   const float* __restrict__ b_off,
                   const float* __restrict__ b_dcn,
                   float* __restrict__ out) {
    __shared__ unsigned int smem4[SMEM_U32];
    unsigned short* halo   = (unsigned short*)smem4;                 // conv phase
    unsigned int*   offsYX = smem4;                                  // [64][73] u32
    unsigned short* maskL  = (unsigned short*)smem4 + MASKL_OFF_U16; // [64][74] u16
    unsigned short* vbuf   = (unsigned short*)smem4 + VBUF_OFF_U16;  // [64][VROW]

    const int b  = blockIdx.z;
    const int h0 = blockIdx.y * 8;
    const int w0 = blockIdx.x * 8;
    const int t  = threadIdx.x;
    const int wv   = t >> 6;
    const int lane = t & 63;
    const int n    = lane & 15;
    const int kg   = lane >> 4;

    // ---- stage halo: 100 pixels x 8 chunks of 8 bf16 ----
    for (int task = t; task < 800; task += 256) {
        const int pix = task >> 3, ch = task & 7;
        const int ry = pix / 10, rx = pix % 10;
        const int gh = h0 - 1 + ry, gw = w0 - 1 + rx;
        float4 v = make_float4(0.f, 0.f, 0.f, 0.f);
        if (gh >= 0 && gh < Hh && gw >= 0 && gw < Ww)
            v = *(const float4*)(featT + ((((size_t)b * Hh) + gh) * Ww + gw) * CINc + ch * 8);
        *(float4*)(halo + pix * 72 + ch * 8) = v;
    }
    __syncthreads();

    // ---- conv phase: M=256(pad of 216), N=64, K=576 ----
    const int bbase0 = (((n >> 3) * 10) + (n & 7)) * 72 + kg * 8;

    f32x4 cacc[4][4] = {};
    bf16x8 af[3][4];
    #pragma unroll
    for (int i = 0; i < 4; ++i)
        af[0][i] = *(const bf16x8*)(wofrag + (((size_t)0 * 16 + wv + 4 * i) * 64 + lane) * 8);
    #pragma unroll
    for (int i = 0; i < 4; ++i)
        af[1][i] = *(const bf16x8*)(wofrag + (((size_t)1 * 16 + wv + 4 * i) * 64 + lane) * 8);

    #pragma unroll
    for (int s = 0; s < 18; ++s) {
        if (s + 2 < 18) {
            #pragma unroll
            for (int i = 0; i < 4; ++i)
                af[(s + 2) % 3][i] = *(const bf16x8*)(wofrag +
                    (((size_t)(s + 2) * 16 + wv + 4 * i) * 64 + lane) * 8);
        }
        const int kp = s >> 1, ks = s & 1;
        const int ky = kp / 3, kx = kp % 3;
        #pragma unroll
        for (int nt = 0; nt < 4; ++nt) {
            const bf16x8 bfr = *(const bf16x8*)(halo + bbase0 + nt * 1440 +
                                                (ky * 10 + kx) * 72 + ks * 32);
            #pragma unroll
            for (int i = 0; i < 4; ++i)
                cacc[i][nt] = __builtin_amdgcn_mfma_f32_16x16x32_bf16(af[s % 3][i], bfr, cacc[i][nt], 0, 0, 0);
        }
    }
    __syncthreads();   // WAR: halo reads done before offsYX overwrites it

    // ---- conv epilogue: bias (+sigmoid for mask) -> offsYX/maskL LDS ----
    #pragma unroll
    for (int i = 0; i < 4; ++i) {
        const int mt = wv + 4 * i;
        #pragma unroll
        for (int nt = 0; nt < 4; ++nt) {
            const int p = nt * 16 + n;
            if (mt < 9) {
                // co = mt*16+kg*4+{0..3} all < 144: (dy,dx) pairs -> u32 plane
                const int cob = mt * 16 + kg * 4;
                const int gkA = cob >> 1;
                const float v0 = cacc[i][nt][0] + b_off[cob + 0];
                const float v1 = cacc[i][nt][1] + b_off[cob + 1];
                const float v2 = cacc[i][nt][2] + b_off[cob + 2];
                const float v3 = cacc[i][nt][3] + b_off[cob + 3];
                unsigned int w01, w23;
                asm("v_cvt_pk_bf16_f32 %0, %1, %2" : "=v"(w01) : "v"(v0), "v"(v1));
                asm("v_cvt_pk_bf16_f32 %0, %1, %2" : "=v"(w23) : "v"(v2), "v"(v3));
                offsYX[p * 73 + gkA]     = w01;
                offsYX[p * 73 + gkA + 1] = w23;
            } else {
                #pragma unroll
                for (int r = 0; r < 4; ++r) {
                    const int co = mt * 16 + kg * 4 + r;
                    if (co < COFF) {
                        float v = cacc[i][nt][r] + b_off[co];
                        v = 1.f / (1.f + expf(-v));
                        maskL[p * 74 + (co - 144)] = f2bf(v);
                    }
                }
            }
        }
    }
    __syncthreads();

    // ---- DCN: 6 K-windows of 96 (12 (g,k)-units); sample -> GEMM ----
    f32x4 dacc[4] = {};
    const int p_t = t & 63;
    const int h_s = h0 + (p_t >> 3);
    const int w_s = w0 + (p_t & 7);

    for (int c = 0; c < NWIN; ++c) {
        // -------- ISSUE phase: 3 offset reads + 12 gathers in flight --------
        float cf[3][4];
        uint4 q[3][4];
        #pragma unroll
        for (int it = 0; it < 3; ++it) {
            const int u = c * WU + wv + it * 4;
            const int g = u / 9;
            const int k = u % 9;

            const unsigned int yx = offsYX[p_t * 73 + u];
            const float dy   = blo(yx);
            const float dx   = bhi(yx);
            const float mask = bf2f(maskL[p_t * 74 + u]);

            const float py  = (float)h_s + (float)(k / 3 - 1) + dy;
            const float pxx = (float)w_s + (float)(k % 3 - 1) + dx;
            const float y0f = floorf(py), x0f = floorf(pxx);
            const float ly = py - y0f, lx = pxx - x0f;
            const int y0 = (int)y0f, x0i = (int)x0f;
            const int y1 = y0 + 1,  x1  = x0i + 1;

            const float vy0 = (y0 >= 0 && y0 < Hh) ? 1.f : 0.f;
            const float vy1 = (y1 >= 0 && y1 < Hh) ? 1.f : 0.f;
            const float vx0 = (x0i >= 0 && x0i < Ww) ? 1.f : 0.f;
            const float vx1 = (x1 >= 0 && x1 < Ww) ? 1.f : 0.f;

            cf[it][0] = (1.f - ly) * (1.f - lx) * vy0 * vx0 * mask;
            cf[it][1] = (1.f - ly) * lx         * vy0 * vx1 * mask;
            cf[it][2] = ly         * (1.f - lx) * vy1 * vx0 * mask;
            cf[it][3] = ly         * lx         * vy1 * vx1 * mask;

            const int y0c = min(max(y0, 0), Hh - 1), y1c = min(max(y1, 0), Hh - 1);
            const int x0c = min(max(x0i, 0), Ww - 1), x1c = min(max(x1, 0), Ww - 1);

            const unsigned short* xb = xG + ((size_t)b * Gg + g) * HW * 8;
            q[it][0] = *(const uint4*)(xb + ((size_t)y0c * Ww + x0c) * 8);
            q[it][1] = *(const uint4*)(xb + ((size_t)y0c * Ww + x1c) * 8);
            q[it][2] = *(const uint4*)(xb + ((size_t)y1c * Ww + x0c) * 8);
            q[it][3] = *(const uint4*)(xb + ((size_t)y1c * Ww + x1c) * 8);
        }

        // -------- BLEND phase: consume gathers, write vbuf ------------------
        #pragma unroll
        for (int it = 0; it < 3; ++it) {
            unsigned int rr0, rr1, rr2, rr3;
            BLEND_J(rr0, q[it][0].x, q[it][1].x, q[it][2].x, q[it][3].x,
                    cf[it][0], cf[it][1], cf[it][2], cf[it][3]);
            BLEND_J(rr1, q[it][0].y, q[it][1].y, q[it][2].y, q[it][3].y,
                    cf[it][0], cf[it][1], cf[it][2], cf[it][3]);
            BLEND_J(rr2, q[it][0].z, q[it][1].z, q[it][2].z, q[it][3].z,
                    cf[it][0], cf[it][1], cf[it][2], cf[it][3]);
            BLEND_J(rr3, q[it][0].w, q[it][1].w, q[it][2].w, q[it][3].w,
                    cf[it][0], cf[it][1], cf[it][2], cf[it][3]);
            uint4 res; res.x = rr0; res.y = rr1; res.z = rr2; res.w = rr3;
            *(uint4*)(vbuf + (size_t)p_t * VROW + (wv + it * 4) * 8) = res;
        }

        // prefetch this window's 3 A-fragments (global, L2) before the barrier
        bf16x8 afr[3];
        #pragma unroll
        for (int s = 0; s < 3; ++s)
            afr[s] = *(const bf16x8*)(wfrag + (((size_t)(c * 3 + s) * 4 + wv) * 64 + lane) * 8);

        __syncthreads();

        // GEMM over this window: 3 k-steps
        #pragma unroll
        for (int s = 0; s < 3; ++s) {
            #pragma unroll
            for (int nt = 0; nt < 4; ++nt) {
                const bf16x8 bfr = *(const bf16x8*)(vbuf + (nt * 16 + n) * VROW + s * 32 + kg * 8);
                dacc[nt] = __builtin_amdgcn_mfma_f32_16x16x32_bf16(afr[s], bfr, dacc[nt], 0, 0, 0);
            }
        }
        __syncthreads();
    }

    // ---- final epilogue: C/D col=lane&15 (pixel-in-ntile), row=kg*4+r (o) ----
    #pragma unroll
    for (int nt = 0; nt < 4; ++nt) {
        const int p = nt * 16 + n;
        const int h = h0 + (p >> 3);
        const int w = w0 + (p & 7);
        #pragma unroll
        for (int r = 0; r < 4; ++r) {
            const int o = wv * 16 + kg * 4 + r;
            out[(((size_t)b * CINc + o) * HW) + h * Ww + w] = dacc[nt][r] + b_dcn[o];
        }
    }
}

extern "C" void kernel_launch(void* const* d_in, const int* in_sizes, int n_in,
                              void* d_out, int out_size, void* d_ws, size_t ws_size,
                              hipStream_t stream) {
    const float* x     = (const float*)d_in[0];
    const float* feat  = (const float*)d_in[1];
    const float* w_off = (const float*)d_in[2];
    const float* b_off = (const float*)d_in[3];
    const float* w_dcn = (const float*)d_in[4];
    const float* b_dcn = (const float*)d_in[5];
    float* out = (float*)d_out;

    // ws layout (ushort elements): featT, xG, wofrag, wfrag  (~26.6 MB)
    unsigned short* featT  = (unsigned short*)d_ws;                // 6,553,600
    unsigned short* xG     = featT + (size_t)Bn * HW * CINc;       // 6,553,600
    unsigned short* wofrag = xG + (size_t)Bn * HW * CINc;          // 147,456
    unsigned short* wfrag  = wofrag + (size_t)147456;              // 36,864

    prep_kernel<<<dim3(1780), 256, 0, stream>>>(
        feat, x, w_off, w_dcn, featT, xG, wofrag, wfrag);
    dcnpack_fused<<<dim3(Ww / 8, Hh / 8, Bn), 256, 0, stream>>>(
        featT, xG, wofrag, wfrag, b_off, b_dcn, out);
}

// Round 8
// 230.116 us; speedup vs baseline: 1.0156x; 1.0156x over previous
//
#include <hip/hip_runtime.h>
#include <math.h>

#define Bn   4
#define CINc 64
#define Hh   160
#define Ww   160
#define Gg   8
#define HW   (Hh * 160)     // 25600
#define COFF 216

// ---- DCN window split: 6 windows x 12 (g,k)-units (3 k-steps of 32) --------
#define NWIN 6
#define WU   12
#define VROW 100            // vbuf row stride u16 (200B rows: lane*50%32 -> 2-way)

// ---- single-union LDS region (disjoint lifetimes alias) --------------------
// halo   : 100*72 u16 = 14400 B   [stage .. conv MFMA end]   (aliases offsYX)
// offsYX : u32 [64][73] = 18688 B [conv epilogue .. last window issue]
// maskL  : u16 [64][74] =  9472 B [conv epilogue .. last window issue]
// vbuf   : u16 [64][VROW]=12800 B [window issue .. gemm]
// total = 40960 B exactly -> 4 blocks/CU (160 KiB / 40960 = 4.0)
#define SMEM_U32 10240           // 40960 B
#define MASKL_OFF_U16 9344       // 18688 B / 2
#define VBUF_OFF_U16  14080      // (18688+9472) / 2

typedef short bf16x8 __attribute__((ext_vector_type(8)));
typedef float f32x4  __attribute__((ext_vector_type(4)));

static __device__ __forceinline__ unsigned short f2bf(float f) {
    unsigned int u = __float_as_uint(f);
    u = (u + 0x7fffu + ((u >> 16) & 1u)) >> 16;
    return (unsigned short)u;
}
static __device__ __forceinline__ float bf2f(unsigned short s) {
    return __uint_as_float(((unsigned int)s) << 16);
}
static __device__ __forceinline__ float blo(unsigned int u) {
    return __uint_as_float(u << 16);
}
static __device__ __forceinline__ float bhi(unsigned int u) {
    return __uint_as_float(u & 0xffff0000u);
}

// ---------- Prep v4: LDS-free streaming transpose + weight repacks ----------
__global__ __launch_bounds__(256)
void prep_kernel(const float* __restrict__ feat, const float* __restrict__ x,
                 const float* __restrict__ w_off, const float* __restrict__ w_dcn,
                 unsigned short* __restrict__ featT, unsigned short* __restrict__ xG,
                 unsigned short* __restrict__ wofrag, unsigned short* __restrict__ wfrag) {
    const int blk = blockIdx.x;
    const int t = threadIdx.x;
    if (blk < 800) {
        const int b  = blk / 200;
        const int q  = (blk % 200) * 32 + (t >> 3);
        const int cj = t & 7;
        const float* fb = feat + (size_t)b * CINc * HW;
        float4 v[8];
        #pragma unroll
        for (int m = 0; m < 8; ++m)
            v[m] = *(const float4*)(fb + (size_t)(cj * 8 + m) * HW + q * 4);
        uint4* dst = (uint4*)featT + ((size_t)b * HW + q * 4) * 8 + cj;
        #pragma unroll
        for (int k = 0; k < 4; ++k) {
            float e[8];
            #pragma unroll
            for (int m = 0; m < 8; ++m) {
                const float4 vv = v[m];
                e[m] = (k == 0) ? vv.x : (k == 1) ? vv.y : (k == 2) ? vv.z : vv.w;
            }
            unsigned int d0, d1, d2, d3;
            asm("v_cvt_pk_bf16_f32 %0, %1, %2" : "=v"(d0) : "v"(e[0]), "v"(e[1]));
            asm("v_cvt_pk_bf16_f32 %0, %1, %2" : "=v"(d1) : "v"(e[2]), "v"(e[3]));
            asm("v_cvt_pk_bf16_f32 %0, %1, %2" : "=v"(d2) : "v"(e[4]), "v"(e[5]));
            asm("v_cvt_pk_bf16_f32 %0, %1, %2" : "=v"(d3) : "v"(e[6]), "v"(e[7]));
            uint4 r4; r4.x = d0; r4.y = d1; r4.z = d2; r4.w = d3;
            dst[(size_t)k * 8] = r4;
        }
    } else if (blk < 1600) {
        const int r  = blk - 800;
        const int bg = r / 25;
        const int q  = (r % 25) * 256 + t;
        const float* xb = x + ((size_t)(bg >> 3) * CINc + (size_t)(bg & 7) * 8) * HW;
        float4 v[8];
        #pragma unroll
        for (int cg = 0; cg < 8; ++cg)
            v[cg] = *(const float4*)(xb + (size_t)cg * HW + q * 4);
        uint4* dst = (uint4*)xG + (size_t)bg * HW + q * 4;
        #pragma unroll
        for (int k = 0; k < 4; ++k) {
            float e[8];
            #pragma unroll
            for (int cg = 0; cg < 8; ++cg) {
                const float4 vv = v[cg];
                e[cg] = (k == 0) ? vv.x : (k == 1) ? vv.y : (k == 2) ? vv.z : vv.w;
            }
            unsigned int d0, d1, d2, d3;
            asm("v_cvt_pk_bf16_f32 %0, %1, %2" : "=v"(d0) : "v"(e[0]), "v"(e[1]));
            asm("v_cvt_pk_bf16_f32 %0, %1, %2" : "=v"(d1) : "v"(e[2]), "v"(e[3]));
            asm("v_cvt_pk_bf16_f32 %0, %1, %2" : "=v"(d2) : "v"(e[4]), "v"(e[5]));
            asm("v_cvt_pk_bf16_f32 %0, %1, %2" : "=v"(d3) : "v"(e[6]), "v"(e[7]));
            uint4 r4; r4.x = d0; r4.y = d1; r4.z = d2; r4.w = d3;
            dst[k] = r4;
        }
    } else {
        for (int e = (blk - 1600) * 256 + t; e < 147456 + 36864; e += 180 * 256) {
            if (e < 147456) {
                const int j    = e & 7;
                const int lane = (e >> 3) & 63;
                const int rest = e >> 9;
                const int mt = rest & 15;
                const int q  = rest >> 4;
                const int ks = q & 1;
                const int kp = q >> 1;
                const int co = mt * 16 + (lane & 15);
                const int ci = ks * 32 + (lane >> 4) * 8 + j;
                float v = (co < COFF) ? w_off[(size_t)co * 576 + ci * 9 + kp] : 0.f;
                wofrag[e] = f2bf(v);
            } else {
                const int e2   = e - 147456;
                const int j    = e2 & 7;
                const int lane = (e2 >> 3) & 63;
                const int mt   = (e2 >> 9) & 3;
                const int ks   = e2 >> 11;
                const int m = mt * 16 + (lane & 15);
                const int k = ks * 32 + (lane >> 4) * 8 + j;
                const int g = k / 72, r = k % 72;
                const int kk = r >> 3, cg = r & 7;
                const int ci = g * 8 + cg;
                wfrag[e2] = f2bf(w_dcn[((size_t)m * CINc + ci) * 9 + kk]);
            }
        }
    }
}

#define BLEND_J(out_, w00, w01, w10, w11, c00, c01, c10, c11) {            \
    float vl_ = (c00) * blo(w00) + (c01) * blo(w01)                        \
              + (c10) * blo(w10) + (c11) * blo(w11);                       \
    float vh_ = (c00) * bhi(w00) + (c01) * bhi(w01)                        \
              + (c10) * bhi(w10) + (c11) * bhi(w11);                       \
    asm("v_cvt_pk_bf16_f32 %0, %1, %2" : "=v"(out_) : "v"(vl_), "v"(vh_)); \
}

// ---------- Fused kernel: 6x12-unit windows, 40960B LDS -----------------------
// LAUNCH-BOUNDS LEDGER (the decisive variable):
//   (256,3): VGPR 84, zero spill (R1/R4/R5)        -> use this
//   (256,4): allocator clamps to 64-VGPR bin, spills ~40 regs
//            (R6: FETCH 107MB/WRITE 165MB; R7: 77/99MB) -> never again
// With LDS=40960 (4 blocks/CU fit) and VGPR<=128, occupancy reaches
// 4 blocks/CU under (256,3) anyway -- the bins are {64,128,256}.
// NO s_setprio (R3 spill storm). Spill tripwire: WRITE must be 25.6 MB.
__global__ __launch_bounds__(256, 3)
void dcnpack_fused(const unsigned short* __restrict__ featT,
                   const unsigned short* __restrict__ xG,
                   const unsigned short* __restrict__ wofrag,
                   const unsigned short* __restrict__ wfrag,
                   const float* __restrict__ b_off,
                   const float* __restrict__ b_dcn,
                   float* __restrict__ out) {
    __shared__ unsigned int smem4[SMEM_U32];
    unsigned short* halo   = (unsigned short*)smem4;                 // conv phase
    unsigned int*   offsYX = smem4;                                  // [64][73] u32
    unsigned short* maskL  = (unsigned short*)smem4 + MASKL_OFF_U16; // [64][74] u16
    unsigned short* vbuf   = (unsigned short*)smem4 + VBUF_OFF_U16;  // [64][VROW]

    const int b  = blockIdx.z;
    const int h0 = blockIdx.y * 8;
    const int w0 = blockIdx.x * 8;
    const int t  = threadIdx.x;
    const int wv   = t >> 6;
    const int lane = t & 63;
    const int n    = lane & 15;
    const int kg   = lane >> 4;

    // ---- stage halo: 100 pixels x 8 chunks of 8 bf16 ----
    for (int task = t; task < 800; task += 256) {
        const int pix = task >> 3, ch = task & 7;
        const int ry = pix / 10, rx = pix % 10;
        const int gh = h0 - 1 + ry, gw = w0 - 1 + rx;
        float4 v = make_float4(0.f, 0.f, 0.f, 0.f);
        if (gh >= 0 && gh < Hh && gw >= 0 && gw < Ww)
            v = *(const float4*)(featT + ((((size_t)b * Hh) + gh) * Ww + gw) * CINc + ch * 8);
        *(float4*)(halo + pix * 72 + ch * 8) = v;
    }
    __syncthreads();

    // ---- conv phase: M=256(pad of 216), N=64, K=576 ----
    const int bbase0 = (((n >> 3) * 10) + (n & 7)) * 72 + kg * 8;

    f32x4 cacc[4][4] = {};
    bf16x8 af[3][4];
    #pragma unroll
    for (int i = 0; i < 4; ++i)
        af[0][i] = *(const bf16x8*)(wofrag + (((size_t)0 * 16 + wv + 4 * i) * 64 + lane) * 8);
    #pragma unroll
    for (int i = 0; i < 4; ++i)
        af[1][i] = *(const bf16x8*)(wofrag + (((size_t)1 * 16 + wv + 4 * i) * 64 + lane) * 8);

    #pragma unroll
    for (int s = 0; s < 18; ++s) {
        if (s + 2 < 18) {
            #pragma unroll
            for (int i = 0; i < 4; ++i)
                af[(s + 2) % 3][i] = *(const bf16x8*)(wofrag +
                    (((size_t)(s + 2) * 16 + wv + 4 * i) * 64 + lane) * 8);
        }
        const int kp = s >> 1, ks = s & 1;
        const int ky = kp / 3, kx = kp % 3;
        #pragma unroll
        for (int nt = 0; nt < 4; ++nt) {
            const bf16x8 bfr = *(const bf16x8*)(halo + bbase0 + nt * 1440 +
                                                (ky * 10 + kx) * 72 + ks * 32);
            #pragma unroll
            for (int i = 0; i < 4; ++i)
                cacc[i][nt] = __builtin_amdgcn_mfma_f32_16x16x32_bf16(af[s % 3][i], bfr, cacc[i][nt], 0, 0, 0);
        }
    }
    __syncthreads();   // WAR: halo reads done before offsYX overwrites it

    // ---- conv epilogue: bias (+sigmoid for mask) -> offsYX/maskL LDS ----
    #pragma unroll
    for (int i = 0; i < 4; ++i) {
        const int mt = wv + 4 * i;
        #pragma unroll
        for (int nt = 0; nt < 4; ++nt) {
            const int p = nt * 16 + n;
            if (mt < 9) {
                // co = mt*16+kg*4+{0..3} all < 144: (dy,dx) pairs -> u32 plane
                const int cob = mt * 16 + kg * 4;
                const int gkA = cob >> 1;
                const float v0 = cacc[i][nt][0] + b_off[cob + 0];
                const float v1 = cacc[i][nt][1] + b_off[cob + 1];
                const float v2 = cacc[i][nt][2] + b_off[cob + 2];
                const float v3 = cacc[i][nt][3] + b_off[cob + 3];
                unsigned int w01, w23;
                asm("v_cvt_pk_bf16_f32 %0, %1, %2" : "=v"(w01) : "v"(v0), "v"(v1));
                asm("v_cvt_pk_bf16_f32 %0, %1, %2" : "=v"(w23) : "v"(v2), "v"(v3));
                offsYX[p * 73 + gkA]     = w01;
                offsYX[p * 73 + gkA + 1] = w23;
            } else {
                #pragma unroll
                for (int r = 0; r < 4; ++r) {
                    const int co = mt * 16 + kg * 4 + r;
                    if (co < COFF) {
                        float v = cacc[i][nt][r] + b_off[co];
                        v = 1.f / (1.f + expf(-v));
                        maskL[p * 74 + (co - 144)] = f2bf(v);
                    }
                }
            }
        }
    }
    __syncthreads();

    // ---- DCN: 6 K-windows of 96 (12 (g,k)-units); sample -> GEMM ----
    f32x4 dacc[4] = {};
    const int p_t = t & 63;
    const int h_s = h0 + (p_t >> 3);
    const int w_s = w0 + (p_t & 7);

    for (int c = 0; c < NWIN; ++c) {
        // -------- ISSUE phase: 3 offset reads + 12 gathers in flight --------
        float cf[3][4];
        uint4 q[3][4];
        #pragma unroll
        for (int it = 0; it < 3; ++it) {
            const int u = c * WU + wv + it * 4;
            const int g = u / 9;
            const int k = u % 9;

            const unsigned int yx = offsYX[p_t * 73 + u];
            const float dy   = blo(yx);
            const float dx   = bhi(yx);
            const float mask = bf2f(maskL[p_t * 74 + u]);

            const float py  = (float)h_s + (float)(k / 3 - 1) + dy;
            const float pxx = (float)w_s + (float)(k % 3 - 1) + dx;
            const float y0f = floorf(py), x0f = floorf(pxx);
            const float ly = py - y0f, lx = pxx - x0f;
            const int y0 = (int)y0f, x0i = (int)x0f;
            const int y1 = y0 + 1,  x1  = x0i + 1;

            const float vy0 = (y0 >= 0 && y0 < Hh) ? 1.f : 0.f;
            const float vy1 = (y1 >= 0 && y1 < Hh) ? 1.f : 0.f;
            const float vx0 = (x0i >= 0 && x0i < Ww) ? 1.f : 0.f;
            const float vx1 = (x1 >= 0 && x1 < Ww) ? 1.f : 0.f;

            cf[it][0] = (1.f - ly) * (1.f - lx) * vy0 * vx0 * mask;
            cf[it][1] = (1.f - ly) * lx         * vy0 * vx1 * mask;
            cf[it][2] = ly         * (1.f - lx) * vy1 * vx0 * mask;
            cf[it][3] = ly         * lx         * vy1 * vx1 * mask;

            const int y0c = min(max(y0, 0), Hh - 1), y1c = min(max(y1, 0), Hh - 1);
            const int x0c = min(max(x0i, 0), Ww - 1), x1c = min(max(x1, 0), Ww - 1);

            const unsigned short* xb = xG + ((size_t)b * Gg + g) * HW * 8;
            q[it][0] = *(const uint4*)(xb + ((size_t)y0c * Ww + x0c) * 8);
            q[it][1] = *(const uint4*)(xb + ((size_t)y0c * Ww + x1c) * 8);
            q[it][2] = *(const uint4*)(xb + ((size_t)y1c * Ww + x0c) * 8);
            q[it][3] = *(const uint4*)(xb + ((size_t)y1c * Ww + x1c) * 8);
        }

        // -------- BLEND phase: consume gathers, write vbuf ------------------
        #pragma unroll
        for (int it = 0; it < 3; ++it) {
            unsigned int rr0, rr1, rr2, rr3;
            BLEND_J(rr0, q[it][0].x, q[it][1].x, q[it][2].x, q[it][3].x,
                    cf[it][0], cf[it][1], cf[it][2], cf[it][3]);
            BLEND_J(rr1, q[it][0].y, q[it][1].y, q[it][2].y, q[it][3].y,
                    cf[it][0], cf[it][1], cf[it][2], cf[it][3]);
            BLEND_J(rr2, q[it][0].z, q[it][1].z, q[it][2].z, q[it][3].z,
                    cf[it][0], cf[it][1], cf[it][2], cf[it][3]);
            BLEND_J(rr3, q[it][0].w, q[it][1].w, q[it][2].w, q[it][3].w,
                    cf[it][0], cf[it][1], cf[it][2], cf[it][3]);
            uint4 res; res.x = rr0; res.y = rr1; res.z = rr2; res.w = rr3;
            *(uint4*)(vbuf + (size_t)p_t * VROW + (wv + it * 4) * 8) = res;
        }

        // prefetch this window's 3 A-fragments (global, L2) before the barrier
        bf16x8 afr[3];
        #pragma unroll
        for (int s = 0; s < 3; ++s)
            afr[s] = *(const bf16x8*)(wfrag + (((size_t)(c * 3 + s) * 4 + wv) * 64 + lane) * 8);

        __syncthreads();

        // GEMM over this window: 3 k-steps
        #pragma unroll
        for (int s = 0; s < 3; ++s) {
            #pragma unroll
            for (int nt = 0; nt < 4; ++nt) {
                const bf16x8 bfr = *(const bf16x8*)(vbuf + (nt * 16 + n) * VROW + s * 32 + kg * 8);
                dacc[nt] = __builtin_amdgcn_mfma_f32_16x16x32_bf16(afr[s], bfr, dacc[nt], 0, 0, 0);
            }
        }
        __syncthreads();
    }

    // ---- final epilogue: C/D col=lane&15 (pixel-in-ntile), row=kg*4+r (o) ----
    #pragma unroll
    for (int nt = 0; nt < 4; ++nt) {
        const int p = nt * 16 + n;
        const int h = h0 + (p >> 3);
        const int w = w0 + (p & 7);
        #pragma unroll
        for (int r = 0; r < 4; ++r) {
            const int o = wv * 16 + kg * 4 + r;
            out[(((size_t)b * CINc + o) * HW) + h * Ww + w] = dacc[nt][r] + b_dcn[o];
        }
    }
}

extern "C" void kernel_launch(void* const* d_in, const int* in_sizes, int n_in,
                              void* d_out, int out_size, void* d_ws, size_t ws_size,
                              hipStream_t stream) {
    const float* x     = (const float*)d_in[0];
    const float* feat  = (const float*)d_in[1];
    const float* w_off = (const float*)d_in[2];
    const float* b_off = (const float*)d_in[3];
    const float* w_dcn = (const float*)d_in[4];
    const float* b_dcn = (const float*)d_in[5];
    float* out = (float*)d_out;

    // ws layout (ushort elements): featT, xG, wofrag, wfrag  (~26.6 MB)
    unsigned short* featT  = (unsigned short*)d_ws;                // 6,553,600
    unsigned short* xG     = featT + (size_t)Bn * HW * CINc;       // 6,553,600
    unsigned short* wofrag = xG + (size_t)Bn * HW * CINc;          // 147,456
    unsigned short* wfrag  = wofrag + (size_t)147456;              // 36,864

    prep_kernel<<<dim3(1780), 256, 0, stream>>>(
        feat, x, w_off, w_dcn, featT, xG, wofrag, wfrag);
    dcnpack_fused<<<dim3(Ww / 8, Hh / 8, Bn), 256, 0, stream>>>(
        featT, xG, wofrag, wfrag, b_off, b_dcn, out);
}

// Round 9
// 190.809 us; speedup vs baseline: 1.2248x; 1.2060x over previous
//
#include <hip/hip_runtime.h>
#include <math.h>

#define Bn   4
#define CINc 64
#define Hh   160
#define Ww   160
#define Gg   8
#define HW   (Hh * 160)     // 25600
#define COFF 216

#define VROW 200            // vbuf row stride u16 (R1-proven)
// ---- LDS layout (53760 B -> 3 blocks/CU; LDS caps residency, so VGPR can
//      grow to the (256,3) cap ~170 for free -- used by the gather pipeline) --
// offsYX : u32 [64][73] = 18688 B   [conv epilogue .. last ISSUE]
// maskL  : u16 [64][74] =  9472 B   (at u16 offset 9344)
// union  : halo 100*72 u16 = 14400 B (conv) | vbuf 64*200 u16 = 25600 B (dcn)
//          at u16 offset 14080
#define SMEM_U16      26880
#define MASKL_OFF_U16 9344
#define UNION_OFF_U16 14080

typedef short bf16x8 __attribute__((ext_vector_type(8)));
typedef float f32x4  __attribute__((ext_vector_type(4)));

static __device__ __forceinline__ unsigned short f2bf(float f) {
    unsigned int u = __float_as_uint(f);
    u = (u + 0x7fffu + ((u >> 16) & 1u)) >> 16;
    return (unsigned short)u;
}
static __device__ __forceinline__ float bf2f(unsigned short s) {
    return __uint_as_float(((unsigned int)s) << 16);
}
static __device__ __forceinline__ float blo(unsigned int u) {
    return __uint_as_float(u << 16);
}
static __device__ __forceinline__ float bhi(unsigned int u) {
    return __uint_as_float(u & 0xffff0000u);
}

// ---------- Prep v4: LDS-free streaming transpose + weight repacks ----------
__global__ __launch_bounds__(256)
void prep_kernel(const float* __restrict__ feat, const float* __restrict__ x,
                 const float* __restrict__ w_off, const float* __restrict__ w_dcn,
                 unsigned short* __restrict__ featT, unsigned short* __restrict__ xG,
                 unsigned short* __restrict__ wofrag, unsigned short* __restrict__ wfrag) {
    const int blk = blockIdx.x;
    const int t = threadIdx.x;
    if (blk < 800) {
        const int b  = blk / 200;
        const int q  = (blk % 200) * 32 + (t >> 3);
        const int cj = t & 7;
        const float* fb = feat + (size_t)b * CINc * HW;
        float4 v[8];
        #pragma unroll
        for (int m = 0; m < 8; ++m)
            v[m] = *(const float4*)(fb + (size_t)(cj * 8 + m) * HW + q * 4);
        uint4* dst = (uint4*)featT + ((size_t)b * HW + q * 4) * 8 + cj;
        #pragma unroll
        for (int k = 0; k < 4; ++k) {
            float e[8];
            #pragma unroll
            for (int m = 0; m < 8; ++m) {
                const float4 vv = v[m];
                e[m] = (k == 0) ? vv.x : (k == 1) ? vv.y : (k == 2) ? vv.z : vv.w;
            }
            unsigned int d0, d1, d2, d3;
            asm("v_cvt_pk_bf16_f32 %0, %1, %2" : "=v"(d0) : "v"(e[0]), "v"(e[1]));
            asm("v_cvt_pk_bf16_f32 %0, %1, %2" : "=v"(d1) : "v"(e[2]), "v"(e[3]));
            asm("v_cvt_pk_bf16_f32 %0, %1, %2" : "=v"(d2) : "v"(e[4]), "v"(e[5]));
            asm("v_cvt_pk_bf16_f32 %0, %1, %2" : "=v"(d3) : "v"(e[6]), "v"(e[7]));
            uint4 r4; r4.x = d0; r4.y = d1; r4.z = d2; r4.w = d3;
            dst[(size_t)k * 8] = r4;
        }
    } else if (blk < 1600) {
        const int r  = blk - 800;
        const int bg = r / 25;
        const int q  = (r % 25) * 256 + t;
        const float* xb = x + ((size_t)(bg >> 3) * CINc + (size_t)(bg & 7) * 8) * HW;
        float4 v[8];
        #pragma unroll
        for (int cg = 0; cg < 8; ++cg)
            v[cg] = *(const float4*)(xb + (size_t)cg * HW + q * 4);
        uint4* dst = (uint4*)xG + (size_t)bg * HW + q * 4;
        #pragma unroll
        for (int k = 0; k < 4; ++k) {
            float e[8];
            #pragma unroll
            for (int cg = 0; cg < 8; ++cg) {
                const float4 vv = v[cg];
                e[cg] = (k == 0) ? vv.x : (k == 1) ? vv.y : (k == 2) ? vv.z : vv.w;
            }
            unsigned int d0, d1, d2, d3;
            asm("v_cvt_pk_bf16_f32 %0, %1, %2" : "=v"(d0) : "v"(e[0]), "v"(e[1]));
            asm("v_cvt_pk_bf16_f32 %0, %1, %2" : "=v"(d1) : "v"(e[2]), "v"(e[3]));
            asm("v_cvt_pk_bf16_f32 %0, %1, %2" : "=v"(d2) : "v"(e[4]), "v"(e[5]));
            asm("v_cvt_pk_bf16_f32 %0, %1, %2" : "=v"(d3) : "v"(e[6]), "v"(e[7]));
            uint4 r4; r4.x = d0; r4.y = d1; r4.z = d2; r4.w = d3;
            dst[k] = r4;
        }
    } else {
        for (int e = (blk - 1600) * 256 + t; e < 147456 + 36864; e += 180 * 256) {
            if (e < 147456) {
                const int j    = e & 7;
                const int lane = (e >> 3) & 63;
                const int rest = e >> 9;
                const int mt = rest & 15;
                const int q  = rest >> 4;
                const int ks = q & 1;
                const int kp = q >> 1;
                const int co = mt * 16 + (lane & 15);
                const int ci = ks * 32 + (lane >> 4) * 8 + j;
                float v = (co < COFF) ? w_off[(size_t)co * 576 + ci * 9 + kp] : 0.f;
                wofrag[e] = f2bf(v);
            } else {
                const int e2   = e - 147456;
                const int j    = e2 & 7;
                const int lane = (e2 >> 3) & 63;
                const int mt   = (e2 >> 9) & 3;
                const int ks   = e2 >> 11;
                const int m = mt * 16 + (lane & 15);
                const int k = ks * 32 + (lane >> 4) * 8 + j;
                const int g = k / 72, r = k % 72;
                const int kk = r >> 3, cg = r & 7;
                const int ci = g * 8 + cg;
                wfrag[e2] = f2bf(w_dcn[((size_t)m * CINc + ci) * 9 + kk]);
            }
        }
    }
}

#define BLEND_J(out_, w00, w01, w10, w11, c00, c01, c10, c11) {            \
    float vl_ = (c00) * blo(w00) + (c01) * blo(w01)                        \
              + (c10) * blo(w10) + (c11) * blo(w11);                       \
    float vh_ = (c00) * bhi(w00) + (c01) * bhi(w01)                        \
              + (c10) * bhi(w10) + (c11) * bhi(w11);                       \
    asm("v_cvt_pk_bf16_f32 %0, %1, %2" : "=v"(out_) : "v"(vl_), "v"(vh_)); \
}

// ISSUE(cw): offset reads + address/coeff math + 24 gathers for window cw.
// cw must fold to a compile-time constant (loop unrolled) so g,k,k/3 fold.
#define ISSUE(cw) do {                                                        \
    _Pragma("unroll")                                                         \
    for (int it = 0; it < 6; ++it) {                                          \
        const int u = (cw) * 24 + wv + it * 4;                                \
        const int g = u / 9;                                                  \
        const int k = u % 9;                                                  \
        const unsigned int yx = offsYX[p_t * 73 + u];                         \
        const float dy   = blo(yx);                                           \
        const float dx   = bhi(yx);                                           \
        const float mask = bf2f(maskL[p_t * 74 + u]);                         \
        const float py  = (float)(h_s + (k / 3 - 1)) + dy;                    \
        const float pxx = (float)(w_s + (k % 3 - 1)) + dx;                    \
        const float y0f = floorf(py), x0f = floorf(pxx);                      \
        const float ly = py - y0f, lx = pxx - x0f;                            \
        const int y0 = (int)y0f, x0i = (int)x0f;                              \
        const float vy0 = (y0 >= 0 && y0 < Hh) ? 1.f : 0.f;                   \
        const float vy1 = (y0 >= -1 && y0 < Hh - 1) ? 1.f : 0.f;              \
        const float vx0 = (x0i >= 0 && x0i < Ww) ? 1.f : 0.f;                 \
        const float vx1 = (x0i >= -1 && x0i < Ww - 1) ? 1.f : 0.f;            \
        const float m1ly = 1.f - ly, m1lx = 1.f - lx;                         \
        cf[it][0] = m1ly * m1lx * vy0 * vx0 * mask;                           \
        cf[it][1] = m1ly * lx   * vy0 * vx1 * mask;                           \
        cf[it][2] = ly   * m1lx * vy1 * vx0 * mask;                           \
        cf[it][3] = ly   * lx   * vy1 * vx1 * mask;                           \
        const int y0c = min(max(y0, 0), Hh - 1);                              \
        const int x0c = min(max(x0i, 0), Ww - 1);                             \
        const int dys = (y0 >= 0 && y0 < Hh - 1) ? Ww * 8 : 0;                \
        const int dxs = (x0i >= 0 && x0i < Ww - 1) ? 8 : 0;                   \
        const unsigned short* xb = xG + ((size_t)b * Gg + g) * HW * 8         \
                                 + ((size_t)y0c * Ww + x0c) * 8;              \
        q[it][0] = *(const uint4*)(xb);                                       \
        q[it][1] = *(const uint4*)(xb + dxs);                                 \
        q[it][2] = *(const uint4*)(xb + dys);                                 \
        q[it][3] = *(const uint4*)(xb + dys + dxs);                           \
    }                                                                         \
} while (0)

// ---------- Fused kernel: 3x24 windows + cross-window gather pipeline -------
// STRUCTURE LEDGER: 24-unit windows 96us (R1) | 12-unit windows 141us (R7/R8)
//   -> big gather batches win; do NOT re-shrink windows.
// LAUNCH BOUNDS: (256,3) only. (256,4) clamps to 64 VGPR + spills (R6/R7).
// NO s_setprio (R3 spill storm). Spill tripwire: WRITE must stay 25.6 MB.
// LDS caps residency at 3 blocks/CU, so VGPR may grow toward ~170 for free:
// that headroom funds holding next window's q[6][4] across the GEMM.
__global__ __launch_bounds__(256, 3)
void dcnpack_fused(const unsigned short* __restrict__ featT,
                   const unsigned short* __restrict__ xG,
                   const unsigned short* __restrict__ wofrag,
                   const unsigned short* __restrict__ wfrag,
                   const float* __restrict__ b_off,
                   const float* __restrict__ b_dcn,
                   float* __restrict__ out) {
    __shared__ unsigned short smem[SMEM_U16];
    unsigned int*   offsYX = (unsigned int*)smem;            // [64][73] u32
    unsigned short* maskL  = smem + MASKL_OFF_U16;           // [64][74] u16
    unsigned short* halo   = smem + UNION_OFF_U16;           // conv phase
    unsigned short* vbuf   = smem + UNION_OFF_U16;           // dcn phase

    const int b  = blockIdx.z;
    const int h0 = blockIdx.y * 8;
    const int w0 = blockIdx.x * 8;
    const int t  = threadIdx.x;
    const int wv   = t >> 6;
    const int lane = t & 63;
    const int n    = lane & 15;
    const int kg   = lane >> 4;

    // ---- stage halo: 100 pixels x 8 chunks of 8 bf16 ----
    for (int task = t; task < 800; task += 256) {
        const int pix = task >> 3, ch = task & 7;
        const int ry = pix / 10, rx = pix % 10;
        const int gh = h0 - 1 + ry, gw = w0 - 1 + rx;
        float4 v = make_float4(0.f, 0.f, 0.f, 0.f);
        if (gh >= 0 && gh < Hh && gw >= 0 && gw < Ww)
            v = *(const float4*)(featT + ((((size_t)b * Hh) + gh) * Ww + gw) * CINc + ch * 8);
        *(float4*)(halo + pix * 72 + ch * 8) = v;
    }
    __syncthreads();

    // ---- conv phase: M=256(pad of 216), N=64, K=576 ----
    const int bbase0 = (((n >> 3) * 10) + (n & 7)) * 72 + kg * 8;

    f32x4 cacc[4][4] = {};
    bf16x8 af[3][4];
    #pragma unroll
    for (int i = 0; i < 4; ++i)
        af[0][i] = *(const bf16x8*)(wofrag + (((size_t)0 * 16 + wv + 4 * i) * 64 + lane) * 8);
    #pragma unroll
    for (int i = 0; i < 4; ++i)
        af[1][i] = *(const bf16x8*)(wofrag + (((size_t)1 * 16 + wv + 4 * i) * 64 + lane) * 8);

    #pragma unroll
    for (int s = 0; s < 18; ++s) {
        if (s + 2 < 18) {
            #pragma unroll
            for (int i = 0; i < 4; ++i)
                af[(s + 2) % 3][i] = *(const bf16x8*)(wofrag +
                    (((size_t)(s + 2) * 16 + wv + 4 * i) * 64 + lane) * 8);
        }
        const int kp = s >> 1, ks = s & 1;
        const int ky = kp / 3, kx = kp % 3;
        #pragma unroll
        for (int nt = 0; nt < 4; ++nt) {
            const bf16x8 bfr = *(const bf16x8*)(halo + bbase0 + nt * 1440 +
                                                (ky * 10 + kx) * 72 + ks * 32);
            #pragma unroll
            for (int i = 0; i < 4; ++i)
                cacc[i][nt] = __builtin_amdgcn_mfma_f32_16x16x32_bf16(af[s % 3][i], bfr, cacc[i][nt], 0, 0, 0);
        }
    }
    __syncthreads();   // halo reads done (vbuf will overwrite it in DCN phase)

    // ---- conv epilogue: bias (+fast sigmoid for mask) -> offsYX/maskL ----
    #pragma unroll
    for (int i = 0; i < 4; ++i) {
        const int mt = wv + 4 * i;
        #pragma unroll
        for (int nt = 0; nt < 4; ++nt) {
            const int p = nt * 16 + n;
            if (mt < 9) {
                const int cob = mt * 16 + kg * 4;
                const int gkA = cob >> 1;
                const float v0 = cacc[i][nt][0] + b_off[cob + 0];
                const float v1 = cacc[i][nt][1] + b_off[cob + 1];
                const float v2 = cacc[i][nt][2] + b_off[cob + 2];
                const float v3 = cacc[i][nt][3] + b_off[cob + 3];
                unsigned int w01, w23;
                asm("v_cvt_pk_bf16_f32 %0, %1, %2" : "=v"(w01) : "v"(v0), "v"(v1));
                asm("v_cvt_pk_bf16_f32 %0, %1, %2" : "=v"(w23) : "v"(v2), "v"(v3));
                offsYX[p * 73 + gkA]     = w01;
                offsYX[p * 73 + gkA + 1] = w23;
            } else {
                #pragma unroll
                for (int r = 0; r < 4; ++r) {
                    const int co = mt * 16 + kg * 4 + r;
                    if (co < COFF) {
                        const float v = cacc[i][nt][r] + b_off[co];
                        // sigmoid(v) = rcp(1 + 2^(-v*log2e)); err << bf16 ulp
                        const float sg = __builtin_amdgcn_rcpf(
                            1.f + __builtin_amdgcn_exp2f(v * -1.44269504f));
                        maskL[p * 74 + (co - 144)] = f2bf(sg);
                    }
                }
            }
        }
    }
    __syncthreads();

    // ---- DCN: 3 windows of 24 units, software-pipelined gathers ----
    f32x4 dacc[4] = {};
    const int p_t = t & 63;
    const int h_s = h0 + (p_t >> 3);
    const int w_s = w0 + (p_t & 7);

    float cf[6][4];
    uint4 q[6][4];
    ISSUE(0);

    #pragma unroll
    for (int c = 0; c < 3; ++c) {
        // -------- BLEND window c (waits on its gathers), write vbuf ---------
        #pragma unroll
        for (int it = 0; it < 6; ++it) {
            unsigned int rr0, rr1, rr2, rr3;
            BLEND_J(rr0, q[it][0].x, q[it][1].x, q[it][2].x, q[it][3].x,
                    cf[it][0], cf[it][1], cf[it][2], cf[it][3]);
            BLEND_J(rr1, q[it][0].y, q[it][1].y, q[it][2].y, q[it][3].y,
                    cf[it][0], cf[it][1], cf[it][2], cf[it][3]);
            BLEND_J(rr2, q[it][0].z, q[it][1].z, q[it][2].z, q[it][3].z,
                    cf[it][0], cf[it][1], cf[it][2], cf[it][3]);
            BLEND_J(rr3, q[it][0].w, q[it][1].w, q[it][2].w, q[it][3].w,
                    cf[it][0], cf[it][1], cf[it][2], cf[it][3]);
            uint4 res; res.x = rr0; res.y = rr1; res.z = rr2; res.w = rr3;
            *(uint4*)(vbuf + (size_t)p_t * VROW + (wv + it * 4) * 8) = res;
        }

        // A-fragments for window c (issued BEFORE next window's gathers so
        // the GEMM's waitcnt on them does not drain the gather queue)
        bf16x8 afr[6];
        #pragma unroll
        for (int s = 0; s < 6; ++s)
            afr[s] = *(const bf16x8*)(wfrag + (((size_t)(c * 6 + s) * 4 + wv) * 64 + lane) * 8);

        __syncthreads();

        // -------- pipeline: issue window c+1 gathers under GEMM c -----------
        if (c < 2) ISSUE(c + 1);

        // -------- GEMM window c: 6 k-steps ----------------------------------
        #pragma unroll
        for (int s = 0; s < 6; ++s) {
            #pragma unroll
            for (int nt = 0; nt < 4; ++nt) {
                const bf16x8 bfr = *(const bf16x8*)(vbuf + (nt * 16 + n) * VROW + s * 32 + kg * 8);
                dacc[nt] = __builtin_amdgcn_mfma_f32_16x16x32_bf16(afr[s], bfr, dacc[nt], 0, 0, 0);
            }
        }
        __syncthreads();
    }

    // ---- final epilogue: C/D col=lane&15 (pixel-in-ntile), row=kg*4+r (o) ----
    #pragma unroll
    for (int nt = 0; nt < 4; ++nt) {
        const int p = nt * 16 + n;
        const int h = h0 + (p >> 3);
        const int w = w0 + (p & 7);
        #pragma unroll
        for (int r = 0; r < 4; ++r) {
            const int o = wv * 16 + kg * 4 + r;
            out[(((size_t)b * CINc + o) * HW) + h * Ww + w] = dacc[nt][r] + b_dcn[o];
        }
    }
}

extern "C" void kernel_launch(void* const* d_in, const int* in_sizes, int n_in,
                              void* d_out, int out_size, void* d_ws, size_t ws_size,
                              hipStream_t stream) {
    const float* x     = (const float*)d_in[0];
    const float* feat  = (const float*)d_in[1];
    const float* w_off = (const float*)d_in[2];
    const float* b_off = (const float*)d_in[3];
    const float* w_dcn = (const float*)d_in[4];
    const float* b_dcn = (const float*)d_in[5];
    float* out = (float*)d_out;

    // ws layout (ushort elements): featT, xG, wofrag, wfrag  (~26.6 MB)
    unsigned short* featT  = (unsigned short*)d_ws;                // 6,553,600
    unsigned short* xG     = featT + (size_t)Bn * HW * CINc;       // 6,553,600
    unsigned short* wofrag = xG + (size_t)Bn * HW * CINc;          // 147,456
    unsigned short* wfrag  = wofrag + (size_t)147456;              // 36,864

    prep_kernel<<<dim3(1780), 256, 0, stream>>>(
        feat, x, w_off, w_dcn, featT, xG, wofrag, wfrag);
    dcnpack_fused<<<dim3(Ww / 8, Hh / 8, Bn), 256, 0, stream>>>(
        featT, xG, wofrag, wfrag, b_off, b_dcn, out);
}

// Round 10
// 179.399 us; speedup vs baseline: 1.3027x; 1.0636x over previous
//
#include <hip/hip_runtime.h>
#include <math.h>

#define Bn   4
#define CINc 64
#define Hh   160
#define Ww   160
#define Gg   8
#define HW   (Hh * 160)     // 25600
#define COFF 216

#define VROW 200            // vbuf row stride u16 (R1-proven)
// ---- LDS layout: 53760 B -> 3 blocks/CU (R1-proven footprint) --------------
// offsYX : u32 [64][73] = 18688 B   [conv epilogue .. window ISSUEs]
// maskL  : u16 [64][74] =  9472 B   (at u16 offset 9344)
// union  : halo 100*72 u16 = 14400 B (conv) | vbuf 64*200 u16 = 25600 B (dcn)
//          at u16 offset 14080
#define SMEM_U16      26880
#define MASKL_OFF_U16 9344
#define UNION_OFF_U16 14080

typedef short bf16x8 __attribute__((ext_vector_type(8)));
typedef float f32x4  __attribute__((ext_vector_type(4)));

static __device__ __forceinline__ unsigned short f2bf(float f) {
    unsigned int u = __float_as_uint(f);
    u = (u + 0x7fffu + ((u >> 16) & 1u)) >> 16;
    return (unsigned short)u;
}
static __device__ __forceinline__ float bf2f(unsigned short s) {
    return __uint_as_float(((unsigned int)s) << 16);
}
static __device__ __forceinline__ float blo(unsigned int u) {
    return __uint_as_float(u << 16);
}
static __device__ __forceinline__ float bhi(unsigned int u) {
    return __uint_as_float(u & 0xffff0000u);
}

// ---------- Prep v4: LDS-free streaming transpose + weight repacks ----------
__global__ __launch_bounds__(256)
void prep_kernel(const float* __restrict__ feat, const float* __restrict__ x,
                 const float* __restrict__ w_off, const float* __restrict__ w_dcn,
                 unsigned short* __restrict__ featT, unsigned short* __restrict__ xG,
                 unsigned short* __restrict__ wofrag, unsigned short* __restrict__ wfrag) {
    const int blk = blockIdx.x;
    const int t = threadIdx.x;
    if (blk < 800) {
        const int b  = blk / 200;
        const int q  = (blk % 200) * 32 + (t >> 3);
        const int cj = t & 7;
        const float* fb = feat + (size_t)b * CINc * HW;
        float4 v[8];
        #pragma unroll
        for (int m = 0; m < 8; ++m)
            v[m] = *(const float4*)(fb + (size_t)(cj * 8 + m) * HW + q * 4);
        uint4* dst = (uint4*)featT + ((size_t)b * HW + q * 4) * 8 + cj;
        #pragma unroll
        for (int k = 0; k < 4; ++k) {
            float e[8];
            #pragma unroll
            for (int m = 0; m < 8; ++m) {
                const float4 vv = v[m];
                e[m] = (k == 0) ? vv.x : (k == 1) ? vv.y : (k == 2) ? vv.z : vv.w;
            }
            unsigned int d0, d1, d2, d3;
            asm("v_cvt_pk_bf16_f32 %0, %1, %2" : "=v"(d0) : "v"(e[0]), "v"(e[1]));
            asm("v_cvt_pk_bf16_f32 %0, %1, %2" : "=v"(d1) : "v"(e[2]), "v"(e[3]));
            asm("v_cvt_pk_bf16_f32 %0, %1, %2" : "=v"(d2) : "v"(e[4]), "v"(e[5]));
            asm("v_cvt_pk_bf16_f32 %0, %1, %2" : "=v"(d3) : "v"(e[6]), "v"(e[7]));
            uint4 r4; r4.x = d0; r4.y = d1; r4.z = d2; r4.w = d3;
            dst[(size_t)k * 8] = r4;
        }
    } else if (blk < 1600) {
        const int r  = blk - 800;
        const int bg = r / 25;
        const int q  = (r % 25) * 256 + t;
        const float* xb = x + ((size_t)(bg >> 3) * CINc + (size_t)(bg & 7) * 8) * HW;
        float4 v[8];
        #pragma unroll
        for (int cg = 0; cg < 8; ++cg)
            v[cg] = *(const float4*)(xb + (size_t)cg * HW + q * 4);
        uint4* dst = (uint4*)xG + (size_t)bg * HW + q * 4;
        #pragma unroll
        for (int k = 0; k < 4; ++k) {
            float e[8];
            #pragma unroll
            for (int cg = 0; cg < 8; ++cg) {
                const float4 vv = v[cg];
                e[cg] = (k == 0) ? vv.x : (k == 1) ? vv.y : (k == 2) ? vv.z : vv.w;
            }
            unsigned int d0, d1, d2, d3;
            asm("v_cvt_pk_bf16_f32 %0, %1, %2" : "=v"(d0) : "v"(e[0]), "v"(e[1]));
            asm("v_cvt_pk_bf16_f32 %0, %1, %2" : "=v"(d1) : "v"(e[2]), "v"(e[3]));
            asm("v_cvt_pk_bf16_f32 %0, %1, %2" : "=v"(d2) : "v"(e[4]), "v"(e[5]));
            asm("v_cvt_pk_bf16_f32 %0, %1, %2" : "=v"(d3) : "v"(e[6]), "v"(e[7]));
            uint4 r4; r4.x = d0; r4.y = d1; r4.z = d2; r4.w = d3;
            dst[k] = r4;
        }
    } else {
        for (int e = (blk - 1600) * 256 + t; e < 147456 + 36864; e += 180 * 256) {
            if (e < 147456) {
                const int j    = e & 7;
                const int lane = (e >> 3) & 63;
                const int rest = e >> 9;
                const int mt = rest & 15;
                const int q  = rest >> 4;
                const int ks = q & 1;
                const int kp = q >> 1;
                const int co = mt * 16 + (lane & 15);
                const int ci = ks * 32 + (lane >> 4) * 8 + j;
                float v = (co < COFF) ? w_off[(size_t)co * 576 + ci * 9 + kp] : 0.f;
                wofrag[e] = f2bf(v);
            } else {
                const int e2   = e - 147456;
                const int j    = e2 & 7;
                const int lane = (e2 >> 3) & 63;
                const int mt   = (e2 >> 9) & 3;
                const int ks   = e2 >> 11;
                const int m = mt * 16 + (lane & 15);
                const int k = ks * 32 + (lane >> 4) * 8 + j;
                const int g = k / 72, r = k % 72;
                const int kk = r >> 3, cg = r & 7;
                const int ci = g * 8 + cg;
                wfrag[e2] = f2bf(w_dcn[((size_t)m * CINc + ci) * 9 + kk]);
            }
        }
    }
}

#define BLEND_J(out_, w00, w01, w10, w11, c00, c01, c10, c11) {            \
    float vl_ = (c00) * blo(w00) + (c01) * blo(w01)                        \
              + (c10) * blo(w10) + (c11) * blo(w11);                       \
    float vh_ = (c00) * bhi(w00) + (c01) * bhi(w01)                        \
              + (c10) * bhi(w10) + (c11) * bhi(w11);                       \
    asm("v_cvt_pk_bf16_f32 %0, %1, %2" : "=v"(out_) : "v"(vl_), "v"(vh_)); \
}

// ---------- Fused kernel: R4 skeleton + VALU trims --------------------------
// STRUCTURE LEDGER (all measured on this problem):
//   24-unit windows, issue->blend in-window:        96 us   <- THIS
//   12-unit windows (more barriers, small batches): 141 us  (R7/R8)
//   split conv/dcn kernels:                         119 us  (R2)
//   s_setprio around MFMA:                 spill -> 140 us  (R3)
//   reg preload of offsets / (256,4):      spill -> 127 us  (R6)
//   cross-window gather pipeline:          spill -> 132 us  (R9)
// INVARIANT: hipcc pins this kernel at ~84 VGPR and spills rather than
// holding ANY extra state across a barrier. No cross-barrier pipelining,
// no setprio, (256,3) only. Spill tripwire: WRITE must stay 25.6 MB.
__global__ __launch_bounds__(256, 3)
void dcnpack_fused(const unsigned short* __restrict__ featT,
                   const unsigned short* __restrict__ xG,
                   const unsigned short* __restrict__ wofrag,
                   const unsigned short* __restrict__ wfrag,
                   const float* __restrict__ b_off,
                   const float* __restrict__ b_dcn,
                   float* __restrict__ out) {
    __shared__ unsigned short smem[SMEM_U16];
    unsigned int*   offsYX = (unsigned int*)smem;            // [64][73] u32
    unsigned short* maskL  = smem + MASKL_OFF_U16;           // [64][74] u16
    unsigned short* halo   = smem + UNION_OFF_U16;           // conv phase
    unsigned short* vbuf   = smem + UNION_OFF_U16;           // dcn phase

    const int b  = blockIdx.z;
    const int h0 = blockIdx.y * 8;
    const int w0 = blockIdx.x * 8;
    const int t  = threadIdx.x;
    const int wv   = t >> 6;
    const int lane = t & 63;
    const int n    = lane & 15;
    const int kg   = lane >> 4;

    // ---- stage halo: 100 pixels x 8 chunks of 8 bf16 ----
    for (int task = t; task < 800; task += 256) {
        const int pix = task >> 3, ch = task & 7;
        const int ry = pix / 10, rx = pix % 10;
        const int gh = h0 - 1 + ry, gw = w0 - 1 + rx;
        float4 v = make_float4(0.f, 0.f, 0.f, 0.f);
        if (gh >= 0 && gh < Hh && gw >= 0 && gw < Ww)
            v = *(const float4*)(featT + ((((size_t)b * Hh) + gh) * Ww + gw) * CINc + ch * 8);
        *(float4*)(halo + pix * 72 + ch * 8) = v;
    }
    __syncthreads();

    // ---- conv phase: M=256(pad of 216), N=64, K=576 ----
    const int bbase0 = (((n >> 3) * 10) + (n & 7)) * 72 + kg * 8;

    f32x4 cacc[4][4] = {};
    bf16x8 af[3][4];
    #pragma unroll
    for (int i = 0; i < 4; ++i)
        af[0][i] = *(const bf16x8*)(wofrag + (((size_t)0 * 16 + wv + 4 * i) * 64 + lane) * 8);
    #pragma unroll
    for (int i = 0; i < 4; ++i)
        af[1][i] = *(const bf16x8*)(wofrag + (((size_t)1 * 16 + wv + 4 * i) * 64 + lane) * 8);

    #pragma unroll
    for (int s = 0; s < 18; ++s) {
        if (s + 2 < 18) {
            #pragma unroll
            for (int i = 0; i < 4; ++i)
                af[(s + 2) % 3][i] = *(const bf16x8*)(wofrag +
                    (((size_t)(s + 2) * 16 + wv + 4 * i) * 64 + lane) * 8);
        }
        const int kp = s >> 1, ks = s & 1;
        const int ky = kp / 3, kx = kp % 3;
        #pragma unroll
        for (int nt = 0; nt < 4; ++nt) {
            const bf16x8 bfr = *(const bf16x8*)(halo + bbase0 + nt * 1440 +
                                                (ky * 10 + kx) * 72 + ks * 32);
            #pragma unroll
            for (int i = 0; i < 4; ++i)
                cacc[i][nt] = __builtin_amdgcn_mfma_f32_16x16x32_bf16(af[s % 3][i], bfr, cacc[i][nt], 0, 0, 0);
        }
    }
    __syncthreads();   // halo reads done (vbuf will overwrite it in DCN phase)

    // ---- conv epilogue: bias (+fast sigmoid for mask) -> offsYX/maskL ----
    #pragma unroll
    for (int i = 0; i < 4; ++i) {
        const int mt = wv + 4 * i;
        #pragma unroll
        for (int nt = 0; nt < 4; ++nt) {
            const int p = nt * 16 + n;
            if (mt < 9) {
                const int cob = mt * 16 + kg * 4;
                const int gkA = cob >> 1;
                const float v0 = cacc[i][nt][0] + b_off[cob + 0];
                const float v1 = cacc[i][nt][1] + b_off[cob + 1];
                const float v2 = cacc[i][nt][2] + b_off[cob + 2];
                const float v3 = cacc[i][nt][3] + b_off[cob + 3];
                unsigned int w01, w23;
                asm("v_cvt_pk_bf16_f32 %0, %1, %2" : "=v"(w01) : "v"(v0), "v"(v1));
                asm("v_cvt_pk_bf16_f32 %0, %1, %2" : "=v"(w23) : "v"(v2), "v"(v3));
                offsYX[p * 73 + gkA]     = w01;
                offsYX[p * 73 + gkA + 1] = w23;
            } else {
                #pragma unroll
                for (int r = 0; r < 4; ++r) {
                    const int co = mt * 16 + kg * 4 + r;
                    if (co < COFF) {
                        const float v = cacc[i][nt][r] + b_off[co];
                        // sigmoid(v) = rcp(1 + 2^(-v*log2e)); err << bf16 ulp
                        const float sg = __builtin_amdgcn_rcpf(
                            1.f + __builtin_amdgcn_exp2f(v * -1.44269504f));
                        maskL[p * 74 + (co - 144)] = f2bf(sg);
                    }
                }
            }
        }
    }
    __syncthreads();

    // ---- DCN: 3 windows of 24 units; issue -> blend -> GEMM per window ----
    f32x4 dacc[4] = {};
    const int p_t = t & 63;
    const int h_s = h0 + (p_t >> 3);
    const int w_s = w0 + (p_t & 7);

    #pragma unroll
    for (int c = 0; c < 3; ++c) {
        // -------- ISSUE: 6 offset/mask reads + 24 gathers, all in flight ----
        float cf[6][4];
        uint4 q[6][4];
        #pragma unroll
        for (int it = 0; it < 6; ++it) {
            const int u = c * 24 + wv + it * 4;   // compile-time c -> g,k fold
            const int g = u / 9;
            const int k = u % 9;

            const unsigned int yx = offsYX[p_t * 73 + u];
            const float dy   = blo(yx);
            const float dx   = bhi(yx);
            const float mask = bf2f(maskL[p_t * 74 + u]);

            const float py  = (float)(h_s + (k / 3 - 1)) + dy;
            const float pxx = (float)(w_s + (k % 3 - 1)) + dx;
            const float y0f = floorf(py), x0f = floorf(pxx);
            const float ly = py - y0f, lx = pxx - x0f;
            const int y0 = (int)y0f, x0i = (int)x0f;

            const float vy0 = (y0 >= 0 && y0 < Hh) ? 1.f : 0.f;
            const float vy1 = (y0 >= -1 && y0 < Hh - 1) ? 1.f : 0.f;
            const float vx0 = (x0i >= 0 && x0i < Ww) ? 1.f : 0.f;
            const float vx1 = (x0i >= -1 && x0i < Ww - 1) ? 1.f : 0.f;

            const float m1ly = 1.f - ly, m1lx = 1.f - lx;
            cf[it][0] = m1ly * m1lx * vy0 * vx0 * mask;
            cf[it][1] = m1ly * lx   * vy0 * vx1 * mask;
            cf[it][2] = ly   * m1lx * vy1 * vx0 * mask;
            cf[it][3] = ly   * lx   * vy1 * vx1 * mask;

            // shared-corner addressing: one clamped base + {0,8}/{0,1280} deltas
            const int y0c = min(max(y0, 0), Hh - 1);
            const int x0c = min(max(x0i, 0), Ww - 1);
            const int dys = (y0 >= 0 && y0 < Hh - 1) ? Ww * 8 : 0;
            const int dxs = (x0i >= 0 && x0i < Ww - 1) ? 8 : 0;

            const unsigned short* xb = xG + ((size_t)b * Gg + g) * HW * 8
                                     + ((size_t)y0c * Ww + x0c) * 8;
            q[it][0] = *(const uint4*)(xb);
            q[it][1] = *(const uint4*)(xb + dxs);
            q[it][2] = *(const uint4*)(xb + dys);
            q[it][3] = *(const uint4*)(xb + dys + dxs);
        }

        // -------- BLEND: consume gathers, write vbuf ------------------------
        #pragma unroll
        for (int it = 0; it < 6; ++it) {
            unsigned int rr0, rr1, rr2, rr3;
            BLEND_J(rr0, q[it][0].x, q[it][1].x, q[it][2].x, q[it][3].x,
                    cf[it][0], cf[it][1], cf[it][2], cf[it][3]);
            BLEND_J(rr1, q[it][0].y, q[it][1].y, q[it][2].y, q[it][3].y,
                    cf[it][0], cf[it][1], cf[it][2], cf[it][3]);
            BLEND_J(rr2, q[it][0].z, q[it][1].z, q[it][2].z, q[it][3].z,
                    cf[it][0], cf[it][1], cf[it][2], cf[it][3]);
            BLEND_J(rr3, q[it][0].w, q[it][1].w, q[it][2].w, q[it][3].w,
                    cf[it][0], cf[it][1], cf[it][2], cf[it][3]);
            uint4 res; res.x = rr0; res.y = rr1; res.z = rr2; res.w = rr3;
            *(uint4*)(vbuf + (size_t)p_t * VROW + (wv + it * 4) * 8) = res;
        }

        // prefetch this window's 6 A-fragments (global, L2) before the barrier
        bf16x8 afr[6];
        #pragma unroll
        for (int s = 0; s < 6; ++s)
            afr[s] = *(const bf16x8*)(wfrag + (((size_t)(c * 6 + s) * 4 + wv) * 64 + lane) * 8);

        __syncthreads();

        // -------- GEMM window c: 6 k-steps ----------------------------------
        #pragma unroll
        for (int s = 0; s < 6; ++s) {
            #pragma unroll
            for (int nt = 0; nt < 4; ++nt) {
                const bf16x8 bfr = *(const bf16x8*)(vbuf + (nt * 16 + n) * VROW + s * 32 + kg * 8);
                dacc[nt] = __builtin_amdgcn_mfma_f32_16x16x32_bf16(afr[s], bfr, dacc[nt], 0, 0, 0);
            }
        }
        __syncthreads();
    }

    // ---- final epilogue: C/D col=lane&15 (pixel-in-ntile), row=kg*4+r (o) ----
    #pragma unroll
    for (int nt = 0; nt < 4; ++nt) {
        const int p = nt * 16 + n;
        const int h = h0 + (p >> 3);
        const int w = w0 + (p & 7);
        #pragma unroll
        for (int r = 0; r < 4; ++r) {
            const int o = wv * 16 + kg * 4 + r;
            out[(((size_t)b * CINc + o) * HW) + h * Ww + w] = dacc[nt][r] + b_dcn[o];
        }
    }
}

extern "C" void kernel_launch(void* const* d_in, const int* in_sizes, int n_in,
                              void* d_out, int out_size, void* d_ws, size_t ws_size,
                              hipStream_t stream) {
    const float* x     = (const float*)d_in[0];
    const float* feat  = (const float*)d_in[1];
    const float* w_off = (const float*)d_in[2];
    const float* b_off = (const float*)d_in[3];
    const float* w_dcn = (const float*)d_in[4];
    const float* b_dcn = (const float*)d_in[5];
    float* out = (float*)d_out;

    // ws layout (ushort elements): featT, xG, wofrag, wfrag  (~26.6 MB)
    unsigned short* featT  = (unsigned short*)d_ws;                // 6,553,600
    unsigned short* xG     = featT + (size_t)Bn * HW * CINc;       // 6,553,600
    unsigned short* wofrag = xG + (size_t)Bn * HW * CINc;          // 147,456
    unsigned short* wfrag  = wofrag + (size_t)147456;              // 36,864

    prep_kernel<<<dim3(1780), 256, 0, stream>>>(
        feat, x, w_off, w_dcn, featT, xG, wofrag, wfrag);
    dcnpack_fused<<<dim3(Ww / 8, Hh / 8, Bn), 256, 0, stream>>>(
        featT, xG, wofrag, wfrag, b_off, b_dcn, out);
}